// Round 4
// baseline (127.314 us; speedup 1.0000x reference)
//
#include <hip/hip_runtime.h>
#include <math.h>

// SphereInterLoss R4: exact 10-NN, x-sorted, deterministic two-phase prune.
//  memset(rank) -> rank_kernel (pairwise count on u64 keys) -> scatter
//  (sorted {x,y,z,|c|^2} + sorted radii) -> knn (8 waves/block, phase 1 =
//  home+-3 chunks + butterfly merge -> tight bound T; phase 2 = static
//  round-robin over chunks passing trunc(gap^2) <= T; butterfly merge;
//  wave 0 evaluates sphere distances) -> fused var+mean.
//  top_dist written in sorted order (variance is permutation-invariant).

#define NB 8
#define NN 4096
#define NCH 64
#define HW 3            // home half-width (chunks)

__device__ __forceinline__ float med3f(float a, float b, float c) {
    return __builtin_amdgcn_fmed3f(a, b, c);
}

// branchless insert into ascending k[0..10], dropping the max
__device__ __forceinline__ void insert11(float k[11], float u) {
#pragma unroll
    for (int j = 10; j >= 1; --j) k[j] = med3f(k[j - 1], k[j], u);
    k[0] = fminf(k[0], u);
}

// ---------------- rank: exact x-rank via pairwise counting ----------------
__global__ __launch_bounds__(256)
void rank_kernel(const float4* __restrict__ sp, int* __restrict__ rank) {
    __shared__ unsigned long long keys[512];
    const int blk = blockIdx.x;
    const int b = blk >> 7, et = (blk >> 3) & 15, jt = blk & 7;
    const float4* spb = sp + ((size_t)b << 12);
    const int j0 = jt * 512;
    for (int j = threadIdx.x; j < 512; j += 256) {
        unsigned u = __float_as_uint(spb[j0 + j].x);
        u = (u >> 31) ? ~u : (u | 0x80000000u);
        keys[j] = ((unsigned long long)u << 12) | (unsigned)(j0 + j);
    }
    __syncthreads();
    const int e = et * 256 + threadIdx.x;
    unsigned ue = __float_as_uint(spb[e].x);
    ue = (ue >> 31) ? ~ue : (ue | 0x80000000u);
    const unsigned long long ke = ((unsigned long long)ue << 12) | (unsigned)e;
    int c0 = 0, c1 = 0, c2 = 0, c3 = 0;
    for (int j = 0; j < 512; j += 4) {
        c0 += (keys[j]     < ke);
        c1 += (keys[j + 1] < ke);
        c2 += (keys[j + 2] < ke);
        c3 += (keys[j + 3] < ke);
    }
    atomicAdd(&rank[(b << 12) + e], c0 + c1 + c2 + c3);
}

// ---------------- scatter: sorted cloud + sorted radii ----------------
__global__ __launch_bounds__(256)
void scatter_kernel(const float4* __restrict__ sp, const int* __restrict__ rank,
                    float4* __restrict__ s4, float* __restrict__ srad) {
    const int idx = blockIdx.x * 256 + threadIdx.x;   // 0..32767
    const int b = idx >> 12;
    float4 s = sp[idx];
    float w = fmaf(s.x, s.x, fmaf(s.y, s.y, s.z * s.z));
    const int r = rank[idx];
    s4[(b << 12) + r] = make_float4(s.x, s.y, s.z, w);
    srad[(b << 12) + r] = s.w;
}

// ---------------- knn: deterministic two-phase ----------------
__global__ __launch_bounds__(512, 4)
void knn_kernel(const float4* __restrict__ s4, const float* __restrict__ srad,
                float* __restrict__ td) {
    __shared__ float mrg[8][11][64];

    const int b = blockIdx.x >> 6, c0 = blockIdx.x & 63;
    const int tid = threadIdx.x, lane = tid & 63, s = tid >> 6;
    const float4* s4b = s4 + ((size_t)b << 12);
    const float* srb = srad + ((size_t)b << 12);

    const int qs = (c0 << 6) + lane;
    const float4 q = s4b[qs];
    const float xqlo = __shfl(q.x, 0, 64);
    const float xqhi = __shfl(q.x, 63, 64);

    float k[11];
#pragma unroll
    for (int j = 0; j < 11; ++j) k[j] = __builtin_inff();

    auto scan_chunk = [&](int c) {
        const int cb = c << 6;
#pragma unroll 8
        for (int i = 0; i < 64; ++i) {
            float4 cc = s4b[cb + i];
            float dot = fmaf(q.x, cc.x, fmaf(q.y, cc.y, q.z * cc.z));
            float d2  = fmaxf(fmaf(-2.0f, dot, q.w + cc.w), 0.0f);
            unsigned u = (__float_as_uint(d2) & 0xFFFFF000u) | (unsigned)(cb + i);
            insert11(k, __uint_as_float(u));
        }
    };

    auto bfly = [&]() {
#pragma unroll
        for (int r = 0; r < 3; ++r) {
#pragma unroll
            for (int j = 0; j < 11; ++j) mrg[s][j][lane] = k[j];
            __syncthreads();
            const int p = s ^ (1 << r);
            float tmp[11];
#pragma unroll
            for (int j = 0; j < 11; ++j) tmp[j] = mrg[p][j][lane];
#pragma unroll
            for (int j = 0; j < 11; ++j) insert11(k, tmp[j]);
            __syncthreads();
        }
    };

    // phase 1: home +-3 chunks, one per wave, then butterfly -> exact
    // k(home window) in every wave
    const int h0 = max(0, c0 - HW), h1 = min(NCH - 1, c0 + HW);
    if (s <= h1 - h0) scan_chunk(h0 + s);
    bfly();

    // bound: candidate in chunk with x-gap g has key >= trunc(g^2)|0, so the
    // chunk is excludable iff trunc(g^2) > max over lanes of k[10]
    float T = k[10];
#pragma unroll
    for (int o = 32; o > 0; o >>= 1) T = fmaxf(T, __shfl_xor(T, o, 64));

    if (s != 0) {
#pragma unroll
        for (int j = 0; j < 11; ++j) k[j] = __builtin_inff();
    }

    // phase 2: identical include-list in all waves, static round-robin
    int pos = 0;
    for (int c = 0; c < NCH; ++c) {
        if (c >= h0 && c <= h1) continue;
        float gap = (c < h0) ? (xqlo - s4b[(c << 6) + 63].x)
                             : (s4b[c << 6].x - xqhi);
        if (gap > 0.0f) {
            float g2t = __uint_as_float(__float_as_uint(gap * gap) & 0xFFFFF000u);
            if (g2t > T) continue;
        }
        if ((pos++ & 7) == s) scan_chunk(c);
    }

    bfly();   // disjoint sets (wave0: home+class0, waves1-7: their class)

    if (s == 0) {
        // k[0] is self (exact d2 == 0 -> key == qs, strictly smallest)
        const float rn = srb[qs];
        float best = __builtin_inff();
#pragma unroll
        for (int j = 1; j <= 10; ++j) {
            int m = (int)(__float_as_uint(k[j]) & 0xFFFu);
            float4 cc = s4b[m];
            float dx = q.x - cc.x, dy = q.y - cc.y, dz = q.z - cc.z;
            float dis = sqrtf(fmaf(dx, dx, fmaf(dy, dy, dz * dz)));
            best = fminf(best, dis - (rn + srb[m]));
        }
        td[(b << 12) + qs] = best;   // sorted order; variance is perm-invariant
    }
}

// ---------------- fused per-batch variance (ddof=1) + mean ----------------
__global__ __launch_bounds__(512)
void var_kernel(const float* __restrict__ td, float* __restrict__ out) {
    __shared__ float part[8];
    const int lane = threadIdx.x & 63, s = threadIdx.x >> 6;  // wave s: batch s
    const float* x = td + (s << 12);

    float sum = 0.0f;
    for (int i = lane; i < NN; i += 64) sum += x[i];
#pragma unroll
    for (int o = 32; o > 0; o >>= 1) sum += __shfl_xor(sum, o, 64);
    const float mu = sum / (float)NN;

    float ss = 0.0f;
    for (int i = lane; i < NN; i += 64) {
        float d = x[i] - mu;
        ss = fmaf(d, d, ss);
    }
#pragma unroll
    for (int o = 32; o > 0; o >>= 1) ss += __shfl_xor(ss, o, 64);
    if (lane == 0) part[s] = ss / (float)(NN - 1);
    __syncthreads();
    if (threadIdx.x == 0) {
        float t = 0.0f;
#pragma unroll
        for (int i = 0; i < NB; ++i) t += part[i];
        out[0] = t / (float)NB;
    }
}

extern "C" void kernel_launch(void* const* d_in, const int* in_sizes, int n_in,
                              void* d_out, int out_size, void* d_ws, size_t ws_size,
                              hipStream_t stream) {
    const float4* spheres = (const float4*)d_in[0];
    char* ws = (char*)d_ws;
    float4* s4   = (float4*)ws;                         // 512 KB
    float*  srad = (float*)(ws + 512 * 1024);           // 128 KB
    int*    rank = (int*)(ws + 640 * 1024);             // 128 KB
    float*  td   = (float*)(ws + 768 * 1024);           // 128 KB
    float*  out  = (float*)d_out;

    hipMemsetAsync(rank, 0, NB * NN * sizeof(int), stream);
    rank_kernel<<<dim3(1024), dim3(256), 0, stream>>>(spheres, rank);
    scatter_kernel<<<dim3(128), dim3(256), 0, stream>>>(spheres, rank, s4, srad);
    knn_kernel<<<dim3(NB * NCH), dim3(512), 0, stream>>>(s4, srad, td);
    var_kernel<<<dim3(1), dim3(512), 0, stream>>>(td, out);
}